// Round 6
// baseline (490.528 us; speedup 1.0000x reference)
//
#include <hip/hip_runtime.h>
#include <cstdint>
#include <cstddef>

#define B_  4
#define C_  512
#define HW_ 4096

typedef unsigned short u16t;
typedef signed char s8t;
typedef __attribute__((ext_vector_type(8))) __bf16 bf16x8;
typedef __attribute__((ext_vector_type(4))) float  f32x4;
typedef __attribute__((ext_vector_type(4))) int    i32x4;

__device__ __forceinline__ u16t f2bft(float f) {            // truncate f32 -> bf16 bits
    return (u16t)(__float_as_uint(f) >> 16);
}
__device__ __forceinline__ float bf2f(u16t h) {
    return __uint_as_float(((unsigned int)h) << 16);
}
__device__ __forceinline__ f32x4 mfma16(bf16x8 a, bf16x8 b, f32x4 c) {
    return __builtin_amdgcn_mfma_f32_16x16x32_bf16(a, b, c, 0, 0, 0);
}
__device__ __forceinline__ i32x4 mfma_i8(i32x4 a, i32x4 b, i32x4 c) {
    return __builtin_amdgcn_mfma_i32_16x16x64_i8(a, b, c, 0, 0, 0);
}
// async global->LDS, 16B per lane; LDS dest = wave-uniform base + lane*16
__device__ __forceinline__ void gl16(const void* g, void* l) {
    __builtin_amdgcn_global_load_lds(
        (__attribute__((address_space(1))) unsigned int*)g,
        (__attribute__((address_space(3))) unsigned int*)l, 16, 0, 0);
}

// ---------------- K0: split 4 weight matrices into bf16 hi/lo ----------------
__global__ __launch_bounds__(256) void split_w(
    const float* __restrict__ wq_, const float* __restrict__ wk_,
    const float* __restrict__ wv_, const float* __restrict__ wp_,
    u16t* __restrict__ out)
{
    int i = blockIdx.x * 256 + threadIdx.x;     // 4*262144 total
    int mat = i >> 18, idx = i & 262143;
    const float* src = (mat == 0) ? wq_ : (mat == 1) ? wk_ : (mat == 2) ? wv_ : wp_;
    float v = src[idx];
    u16t hi = f2bft(v);
    u16t lo = f2bft(v - bf2f(hi));
    out[(size_t)mat * 524288 + idx] = hi;
    out[(size_t)mat * 524288 + 262144 + idx] = lo;
}

// ---------------- K1a: GroupNorm stats: per-(b,g) mean + rsqrt(var+eps) ------
__global__ __launch_bounds__(1024) void gn_stats(
    const float* __restrict__ x, float2* __restrict__ stats)
{
    const int tid = threadIdx.x;
    const int bg = blockIdx.x;            // b*32+g
    const int b = bg >> 5, g = bg & 31;
    const float4* x4 = (const float4*)(x + ((size_t)b * C_ + g * 16) * HW_);
    float s = 0.f, s2 = 0.f;
    for (int i = tid; i < 16384; i += 1024) {
        float4 v = x4[i];
        s  += v.x + v.y + v.z + v.w;
        s2 += v.x * v.x + v.y * v.y + v.z * v.z + v.w * v.w;
    }
    for (int off = 32; off; off >>= 1) { s += __shfl_down(s, off); s2 += __shfl_down(s2, off); }
    __shared__ float rs[16], rs2[16];
    int w = tid >> 6, lane = tid & 63;
    if (lane == 0) { rs[w] = s; rs2[w] = s2; }
    __syncthreads();
    if (tid == 0) {
        float S = 0.f, S2 = 0.f;
        #pragma unroll
        for (int i = 0; i < 16; ++i) { S += rs[i]; S2 += rs2[i]; }
        float mu = S * (1.f / 65536.f);
        float var = S2 * (1.f / 65536.f) - mu * mu;
        stats[bg] = make_float2(mu, 1.f / sqrtf(var + 1e-6f));
    }
}

// ---------------- K1b: GroupNorm apply + transpose -> hn hi/lo [b][p][c] -----
// One block: 16 p x 512 c. LDS u32 tile (hi|lo<<16), padded stride 529.
__global__ __launch_bounds__(256) void gn_apply(
    const float* __restrict__ x, const float* __restrict__ gamma,
    const float* __restrict__ beta, const float2* __restrict__ stats,
    u16t* __restrict__ hn_hi, u16t* __restrict__ hn_lo)
{
    __shared__ unsigned int tile[16 * 529];     // 33856 B
    __shared__ float sa[512], sb[512];
    const int tid = threadIdx.x;
    const int b = blockIdx.y, p0 = blockIdx.x * 16;
    for (int c = tid; c < 512; c += 256) {
        float2 st = stats[b * 32 + (c >> 4)];
        float a = st.y * gamma[c];
        sa[c] = a; sb[c] = beta[c] - st.x * a;
    }
    __syncthreads();
    const float4* x4 = (const float4*)(x + (size_t)b * C_ * HW_);
    const int f4 = tid & 3, cb = tid >> 2;      // cb 0..63
    #pragma unroll
    for (int it = 0; it < 8; ++it) {
        int c = cb + it * 64;
        float4 v = x4[(size_t)c * (HW_ / 4) + (p0 >> 2) + f4];
        float a = sa[c], bo = sb[c];
        float ys[4] = { v.x, v.y, v.z, v.w };
        #pragma unroll
        for (int j = 0; j < 4; ++j) {
            float y = ys[j] * a + bo;
            u16t hi = f2bft(y);
            u16t lo = f2bft(y - bf2f(hi));
            tile[(f4 * 4 + j) * 529 + c] = (unsigned int)hi | ((unsigned int)lo << 16);
        }
    }
    __syncthreads();
    const int p = tid & 15, seg = tid >> 4;     // seg 0..15, 32 c each
    size_t ro = ((size_t)b * HW_ + p0 + p) * C_;
    #pragma unroll
    for (int gg = 0; gg < 4; ++gg) {
        const unsigned int* src = &tile[p * 529 + seg * 32 + gg * 8];
        uint4 va = *(const uint4*)src;
        uint4 vb = *(const uint4*)(src + 4);
        uint4 hi4, lo4;
        hi4.x = (va.x & 0xFFFFu) | (va.y << 16);
        hi4.y = (va.z & 0xFFFFu) | (va.w << 16);
        hi4.z = (vb.x & 0xFFFFu) | (vb.y << 16);
        hi4.w = (vb.z & 0xFFFFu) | (vb.w << 16);
        lo4.x = (va.x >> 16) | (va.y & 0xFFFF0000u);
        lo4.y = (va.z >> 16) | (va.w & 0xFFFF0000u);
        lo4.z = (vb.x >> 16) | (vb.y & 0xFFFF0000u);
        lo4.w = (vb.z >> 16) | (vb.w & 0xFFFF0000u);
        *(uint4*)(hn_hi + ro + seg * 32 + gg * 8) = hi4;
        *(uint4*)(hn_lo + ro + seg * 32 + gg * 8) = lo4;
    }
}

// ---------------- split-GEMM (A=weight hi/lo [o][c], B=act hi/lo [p][c], K=512)
// MODE 0: quant -> i8 centered ints, TRANSPOSED out [p][c]   (Q, K)
// MODE 1: quant -> i8 centered ints, natural out [c][p]      (V)
// MODE 2: + bias + residual -> f32 out [c][p]                (final proj)
template<int MODE>
__global__ __launch_bounds__(256) void gemm512(
    const u16t* __restrict__ Ahi, const u16t* __restrict__ Alo,
    const u16t* __restrict__ Bhi, const u16t* __restrict__ Blo,
    const float* __restrict__ bias, const float* __restrict__ delta,
    const float* __restrict__ zp, s8t* __restrict__ outq,
    float* __restrict__ outf, const float* __restrict__ resid)
{
    __shared__ __align__(16) u16t lds[16384];
    const int tid = threadIdx.x, w = tid >> 6, lane = tid & 63;
    const int lr = lane & 15, gq = lane >> 4, wr = w >> 1, wc = w & 1;
    const int m0 = blockIdx.x * 128, n0 = blockIdx.y * 128, b = blockIdx.z;
    const size_t boff = (size_t)b * HW_ * C_;
    const u16t* gsrc = (w == 0) ? Ahi : (w == 1) ? Alo : (w == 2) ? (Bhi + boff) : (Blo + boff);
    const int rb0 = (w < 2) ? m0 : n0;
    u16t* ldst = lds + w * 4096;
    const int srow = lane >> 2, sch = lane & 3;
    const u16t* sAh = lds; const u16t* sAl = lds + 4096;
    const u16t* sBh = lds + 8192; const u16t* sBl = lds + 12288;
    f32x4 acc[4][4] = {};

    for (int kt = 0; kt < 16; ++kt) {
        const u16t* gk = gsrc + (size_t)(rb0 + srow) * C_ + kt * 32 + sch * 8;
        #pragma unroll
        for (int i = 0; i < 8; ++i) gl16(gk + i * 16 * C_, ldst + i * 512);
        __syncthreads();
        bf16x8 ah[4], al[4], bh[4], bl[4];
        #pragma unroll
        for (int m = 0; m < 4; ++m) {
            int r = wr * 64 + m * 16 + lr;
            ah[m] = *(const bf16x8*)(sAh + r * 32 + gq * 8);
            al[m] = *(const bf16x8*)(sAl + r * 32 + gq * 8);
        }
        #pragma unroll
        for (int n = 0; n < 4; ++n) {
            int r = wc * 64 + n * 16 + lr;
            bh[n] = *(const bf16x8*)(sBh + r * 32 + gq * 8);
            bl[n] = *(const bf16x8*)(sBl + r * 32 + gq * 8);
        }
        #pragma unroll
        for (int m = 0; m < 4; ++m)
            #pragma unroll
            for (int n = 0; n < 4; ++n) {
                acc[m][n] = mfma16(ah[m], bh[n], acc[m][n]);
                acc[m][n] = mfma16(ah[m], bl[n], acc[m][n]);
                acc[m][n] = mfma16(al[m], bh[n], acc[m][n]);
            }
        __syncthreads();
    }

    if constexpr (MODE == 0) {
        const float d = *delta, z = *zp;
        const float rd = 1.0f / d;
        char* T8 = (char*)lds;                   // [p 128][c 128], stride 144
        #pragma unroll
        for (int m = 0; m < 4; ++m)
            #pragma unroll
            for (int n = 0; n < 4; ++n)
                #pragma unroll
                for (int j = 0; j < 4; ++j) {
                    int row = wr * 64 + m * 16 + gq * 4 + j;     // c
                    int col = wc * 64 + n * 16 + lr;             // p
                    float val = acc[m][n][j] + bias[m0 + row];
                    float q = fminf(fmaxf(rintf(val * rd), -z), 255.f - z);
                    T8[col * 144 + row] = (char)(int)q;
                }
        __syncthreads();
        int pl = tid >> 1, hf = tid & 1;
        uint4* dst = (uint4*)(outq + ((size_t)b * HW_ + n0 + pl) * C_ + m0 + hf * 64);
        const uint4* s4 = (const uint4*)(T8 + pl * 144 + hf * 64);
        #pragma unroll
        for (int i = 0; i < 4; ++i) dst[i] = s4[i];
    } else if constexpr (MODE == 1) {
        const float d = *delta, z = *zp;
        const float rd = 1.0f / d;
        char* T8 = (char*)lds;                   // [c 128][p 128], stride 144
        #pragma unroll
        for (int m = 0; m < 4; ++m)
            #pragma unroll
            for (int n = 0; n < 4; ++n)
                #pragma unroll
                for (int j = 0; j < 4; ++j) {
                    int row = wr * 64 + m * 16 + gq * 4 + j;     // c
                    int col = wc * 64 + n * 16 + lr;             // p
                    float val = acc[m][n][j] + bias[m0 + row];
                    float q = fminf(fmaxf(rintf(val * rd), -z), 255.f - z);
                    T8[row * 144 + col] = (char)(int)q;
                }
        __syncthreads();
        int pl = tid >> 1, hf = tid & 1;
        uint4* dst = (uint4*)(outq + ((size_t)b * C_ + m0 + pl) * HW_ + n0 + hf * 64);
        const uint4* s4 = (const uint4*)(T8 + pl * 144 + hf * 64);
        #pragma unroll
        for (int i = 0; i < 4; ++i) dst[i] = s4[i];
    } else {
        #pragma unroll
        for (int m = 0; m < 4; ++m)
            #pragma unroll
            for (int n = 0; n < 4; ++n)
                #pragma unroll
                for (int j = 0; j < 4; ++j) {
                    int row = wr * 64 + m * 16 + gq * 4 + j;
                    int col = wc * 64 + n * 16 + lr;
                    size_t o = ((size_t)b * C_ + m0 + row) * HW_ + n0 + col;
                    outf[o] = acc[m][n][j] + bias[m0 + row] + resid[o];
                }
    }
}

// ---------------- attention scores: S = Qt * Kt^T (i8, both [p][c], K=512) ---
// 256q x 128k tile, 4 waves (2x2), each 128x64; double-buffered prefetch.
// PASS 0: per-row partial (max, sumexp) per 128-col tile -> pml
// PASS 1: w255 = exp(s-m)*rl, round, center -128 -> W8 s8 [b][q][k]
template<int PASS>
__global__ __launch_bounds__(256, 2) void attn_score(
    const s8t* __restrict__ Qt, const s8t* __restrict__ Kt,
    const float* __restrict__ dqp, const float* __restrict__ dkp,
    float2* __restrict__ pml, const float2* __restrict__ ml,
    s8t* __restrict__ W8)
{
    __shared__ __align__(16) char lds[49152];   // 2 x (A 16K + B 8K); P8 256*144 fits
    __shared__ float redm[512], reds[512];
    const int tid = threadIdx.x, w = tid >> 6, lane = tid & 63;
    const int lr = lane & 15, gq = lane >> 4, wr = w >> 1, wc = w & 1;
    const int m0 = blockIdx.x * 256, n0 = blockIdx.y * 128, b = blockIdx.z;
    const size_t bo = (size_t)b * HW_ * C_;
    const int srow = lane >> 2, sch = lane & 3;
    const s8t* Abase = Qt + bo + (size_t)(m0 + w * 64 + srow) * C_ + sch * 16;
    const s8t* Bbase = Kt + bo + (size_t)(n0 + w * 32 + srow) * C_ + sch * 16;
    char* Adst = lds + (w * 64) * 64;           // wave stages A rows [w*64, w*64+64)
    char* Bdst = lds + 16384 + (w * 32) * 64;   // and B rows [w*32, w*32+32)
    i32x4 acc[8][4] = {};

    // prologue: stage kt=0 into buffer 0
    #pragma unroll
    for (int i = 0; i < 4; ++i) gl16(Abase + (size_t)i * 16 * C_, Adst + i * 1024);
    #pragma unroll
    for (int i = 0; i < 2; ++i) gl16(Bbase + (size_t)i * 16 * C_, Bdst + i * 1024);
    __syncthreads();
    int cur = 0;
    for (int kt = 0; kt < 8; ++kt) {
        if (kt < 7) {                           // prefetch next K-step into other buf
            int koff = (kt + 1) * 64;
            char* ad = Adst + (cur ^ 1) * 24576;
            char* bd = Bdst + (cur ^ 1) * 24576;
            #pragma unroll
            for (int i = 0; i < 4; ++i) gl16(Abase + koff + (size_t)i * 16 * C_, ad + i * 1024);
            #pragma unroll
            for (int i = 0; i < 2; ++i) gl16(Bbase + koff + (size_t)i * 16 * C_, bd + i * 1024);
        }
        const char* rb = lds + cur * 24576;
        i32x4 a[8], bb[4];
        #pragma unroll
        for (int m = 0; m < 8; ++m)
            a[m] = *(const i32x4*)(rb + (wr * 128 + m * 16 + lr) * 64 + gq * 16);
        #pragma unroll
        for (int n = 0; n < 4; ++n)
            bb[n] = *(const i32x4*)(rb + 16384 + (wc * 64 + n * 16 + lr) * 64 + gq * 16);
        #pragma unroll
        for (int m = 0; m < 8; ++m)
            #pragma unroll
            for (int n = 0; n < 4; ++n)
                acc[m][n] = mfma_i8(a[m], bb[n], acc[m][n]);
        __syncthreads();                        // drains prefetch vmcnt too
        cur ^= 1;
    }

    const float sc = (*dqp) * (*dkp) * 0.044194173824159216f;  // c^-0.5, C=512
    if constexpr (PASS == 0) {
        #pragma unroll
        for (int m = 0; m < 8; ++m)
            #pragma unroll
            for (int j = 0; j < 4; ++j) {
                float v0 = (float)acc[m][0][j] * sc, v1 = (float)acc[m][1][j] * sc;
                float v2 = (float)acc[m][2][j] * sc, v3 = (float)acc[m][3][j] * sc;
                float mx = fmaxf(fmaxf(v0, v1), fmaxf(v2, v3));
                for (int off = 1; off < 16; off <<= 1) mx = fmaxf(mx, __shfl_xor(mx, off));
                float se = __expf(v0 - mx) + __expf(v1 - mx) + __expf(v2 - mx) + __expf(v3 - mx);
                for (int off = 1; off < 16; off <<= 1) se += __shfl_xor(se, off);
                if (lr == 0) {
                    int r = wr * 128 + m * 16 + gq * 4 + j;
                    redm[r * 2 + wc] = mx; reds[r * 2 + wc] = se;
                }
            }
        __syncthreads();
        {
            float ma = redm[tid * 2], mb = redm[tid * 2 + 1];
            float mm = fmaxf(ma, mb);
            float ss = reds[tid * 2] * __expf(ma - mm) + reds[tid * 2 + 1] * __expf(mb - mm);
            pml[((size_t)b * HW_ + m0 + tid) * 32 + blockIdx.y] = make_float2(mm, ss);
        }
    } else {
        char* P8 = lds;                          // [q 256][k 128], stride 144
        #pragma unroll
        for (int m = 0; m < 8; ++m)
            #pragma unroll
            for (int j = 0; j < 4; ++j) {
                int row = wr * 128 + m * 16 + gq * 4 + j;
                float2 mv = ml[(size_t)b * HW_ + m0 + row];   // (m, rl=1/(l*dw))
                #pragma unroll
                for (int n = 0; n < 4; ++n) {
                    int col = wc * 64 + n * 16 + lr;
                    float sv = __builtin_fmaf((float)acc[m][n][j], sc, -mv.x);
                    float r = rintf(__expf(sv) * mv.y);
                    r = fminf(fmaxf(r, 0.f), 255.f);
                    P8[row * 144 + col] = (char)((int)r - 128);
                }
            }
        __syncthreads();
        int pl = tid >> 1, hf = tid & 1;
        #pragma unroll
        for (int h = 0; h < 2; ++h) {
            uint4* dst = (uint4*)(W8 + ((size_t)b * HW_ + m0 + h * 128 + pl) * HW_ + n0 + hf * 64);
            const uint4* s4 = (const uint4*)(P8 + (h * 128 + pl) * 144 + hf * 64);
            #pragma unroll
            for (int i = 0; i < 4; ++i) dst[i] = s4[i];
        }
    }
}

// ---------------- merge per-tile (m,l) partials -> (m, 1/(l*dw)) -------------
__global__ __launch_bounds__(256) void reduce_ml_k(
    const float2* __restrict__ pml, float2* __restrict__ ml,
    const float* __restrict__ dwp)
{
    int idx = blockIdx.x * 256 + threadIdx.x;   // < B_*HW_
    const float2* p = pml + (size_t)idx * 32;
    float2 vv[32];
    float mm = -3.402823466e38f;
    #pragma unroll
    for (int i = 0; i < 32; ++i) { vv[i] = p[i]; mm = fmaxf(mm, vv[i].x); }
    float l = 0.f;
    #pragma unroll
    for (int i = 0; i < 32; ++i) l += vv[i].y * __expf(vv[i].x - mm);
    ml[idx] = make_float2(mm, 1.0f / (l * (*dwp)));
}

// ---------------- per-(b,c) row sums of centered V ---------------------------
__global__ __launch_bounds__(64) void rowsum_v(
    const s8t* __restrict__ V, int* __restrict__ rsum)
{
    const int row = blockIdx.x, lane = threadIdx.x;   // 2048 rows
    const int4* src = (const int4*)(V + (size_t)row * HW_);
    int s = 0;
    #pragma unroll
    for (int it = 0; it < 4; ++it) {
        int4 v = src[it * 64 + lane];
        int ww[4] = { v.x, v.y, v.z, v.w };
        #pragma unroll
        for (int d = 0; d < 4; ++d) {
            int xv = ww[d];
            s += (int)(s8t)(xv) + (int)(s8t)(xv >> 8)
               + (int)(s8t)(xv >> 16) + (int)(s8t)(xv >> 24);
        }
    }
    #pragma unroll
    for (int off = 32; off; off >>= 1) s += __shfl_down(s, off);
    if (lane == 0) rsum[row] = s;
}

// ---------------- PV: h[c][q] = (VW' + 128*rowsumV) * dv*dw  (i8 MFMA) -------
// double-buffered prefetch, 128x128 tile.
__global__ __launch_bounds__(256) void pv_kernel(
    const s8t* __restrict__ V, const s8t* __restrict__ W8,
    const int* __restrict__ rsum,
    const float* __restrict__ dvp, const float* __restrict__ dwp,
    u16t* __restrict__ h_hi, u16t* __restrict__ h_lo)
{
    __shared__ __align__(16) char lds[34816];   // 2 x 16K stage; epilogue T u16 128*136
    const int tid = threadIdx.x, w = tid >> 6, lane = tid & 63;
    const int lr = lane & 15, gq = lane >> 4, wr = w >> 1, wc = w & 1;
    const int m0 = blockIdx.x * 128, n0 = blockIdx.y * 128, b = blockIdx.z;
    const int srow = lane >> 2, sch = lane & 3;
    const s8t* gbase = (w < 2)
        ? (V  + ((size_t)(b * C_  + m0 + (w & 1) * 64 + srow)) * HW_)
        : (W8 + ((size_t)b * HW_ + n0 + (w & 1) * 64 + srow) * HW_);
    char* ldst = lds + ((w < 2) ? 0 : 8192) + (w & 1) * 4096;
    i32x4 acc[4][4] = {};

    // prologue: stage kt=0 into buffer 0
    {
        const s8t* gk = gbase + sch * 16;
        #pragma unroll
        for (int i = 0; i < 4; ++i) gl16(gk + (size_t)i * 16 * HW_, ldst + i * 1024);
    }
    __syncthreads();
    int cur = 0;
    for (int kt = 0; kt < 64; ++kt) {
        if (kt < 63) {
            const s8t* gk = gbase + (kt + 1) * 64 + sch * 16;
            char* nd = ldst + (cur ^ 1) * 16384;
            #pragma unroll
            for (int i = 0; i < 4; ++i) gl16(gk + (size_t)i * 16 * HW_, nd + i * 1024);
        }
        const char* rb = lds + cur * 16384;
        i32x4 af[4], bf[4];
        #pragma unroll
        for (int m = 0; m < 4; ++m)
            af[m] = *(const i32x4*)(rb + (wr * 64 + m * 16 + lr) * 64 + gq * 16);
        #pragma unroll
        for (int n = 0; n < 4; ++n)
            bf[n] = *(const i32x4*)(rb + 8192 + (wc * 64 + n * 16 + lr) * 64 + gq * 16);
        #pragma unroll
        for (int m = 0; m < 4; ++m)
            #pragma unroll
            for (int n = 0; n < 4; ++n)
                acc[m][n] = mfma_i8(af[m], bf[n], acc[m][n]);
        __syncthreads();
        cur ^= 1;
    }

    const float scl = (*dvp) * (*dwp);
    int rsv[4][4];
    #pragma unroll
    for (int m = 0; m < 4; ++m)
        #pragma unroll
        for (int j = 0; j < 4; ++j)
            rsv[m][j] = rsum[(size_t)b * C_ + m0 + wr * 64 + m * 16 + gq * 4 + j];

    u16t* T = (u16t*)lds;                        // [p 128][c 128], stride 136
    // hi pass
    #pragma unroll
    for (int m = 0; m < 4; ++m)
        #pragma unroll
        for (int n = 0; n < 4; ++n)
            #pragma unroll
            for (int j = 0; j < 4; ++j) {
                int row = wr * 64 + m * 16 + gq * 4 + j;
                int col = wc * 64 + n * 16 + lr;
                float h = (float)(acc[m][n][j] + 128 * rsv[m][j]) * scl;
                T[col * 136 + row] = f2bft(h);
            }
    __syncthreads();
    {
        int pl = tid >> 1, hf = tid & 1;
        uint4* dst = (uint4*)(h_hi + ((size_t)b * HW_ + n0 + pl) * C_ + m0 + hf * 64);
        const uint4* s4 = (const uint4*)(T + pl * 136 + hf * 64);
        #pragma unroll
        for (int i = 0; i < 8; ++i) dst[i] = s4[i];
    }
    __syncthreads();
    // lo pass
    #pragma unroll
    for (int m = 0; m < 4; ++m)
        #pragma unroll
        for (int n = 0; n < 4; ++n)
            #pragma unroll
            for (int j = 0; j < 4; ++j) {
                int row = wr * 64 + m * 16 + gq * 4 + j;
                int col = wc * 64 + n * 16 + lr;
                float h = (float)(acc[m][n][j] + 128 * rsv[m][j]) * scl;
                u16t hi = f2bft(h);
                T[col * 136 + row] = f2bft(h - bf2f(hi));
            }
    __syncthreads();
    {
        int pl = tid >> 1, hf = tid & 1;
        uint4* dst = (uint4*)(h_lo + ((size_t)b * HW_ + n0 + pl) * C_ + m0 + hf * 64);
        const uint4* s4 = (const uint4*)(T + pl * 136 + hf * 64);
        #pragma unroll
        for (int i = 0; i < 8; ++i) dst[i] = s4[i];
    }
}

// ---------------- launcher ---------------------------------------------------
extern "C" void kernel_launch(void* const* d_in, const int* in_sizes, int n_in,
                              void* d_out, int out_size, void* d_ws, size_t ws_size,
                              hipStream_t stream)
{
    const float* x     = (const float*)d_in[0];
    const float* gamma = (const float*)d_in[1];
    const float* beta  = (const float*)d_in[2];
    const float* wq = (const float*)d_in[3];
    const float* bq = (const float*)d_in[4];
    const float* wk = (const float*)d_in[5];
    const float* bk = (const float*)d_in[6];
    const float* wv = (const float*)d_in[7];
    const float* bv = (const float*)d_in[8];
    const float* wp = (const float*)d_in[9];
    const float* bp = (const float*)d_in[10];
    const float* dq = (const float*)d_in[11];
    const float* zq = (const float*)d_in[12];
    const float* dk = (const float*)d_in[13];
    const float* zk = (const float*)d_in[14];
    const float* dv = (const float*)d_in[15];
    const float* zv = (const float*)d_in[16];
    const float* dw = (const float*)d_in[17];
    float* out = (float*)d_out;
    char* ws = (char*)d_ws;
    const size_t MiB = 1048576;

    // Overlay plan (peak 108 MiB + ~141 KB):
    //  [0,4)     wsp (bf16 hi/lo weights)                split_w -> proj
    //  [4,12)    Vq (i8 [c][p])                          gemmV -> pv
    //  [12,76)   W8 (s8 [q][k])                          attn1 -> pv
    //    [12,28) hn_hi, [28,44) hn_lo (dead before attn1)
    //    [44,48) pml (dead before attn1)
    //  [76,108)  hh [76,92), hl [92,108)                 pv -> proj
    //    [76,84) Qt, [84,92) Kt (dead before pv writes hh)
    //  [108,..)  ml 128KB, rsum 8KB, stats 1KB
    u16t* wsp   = (u16t*)ws;
    s8t*  Vq    = (s8t*)(ws + 4 * MiB);
    s8t*  W8    = (s8t*)(ws + 12 * MiB);
    u16t* hn_hi = (u16t*)(ws + 12 * MiB);
    u16t* hn_lo = (u16t*)(ws + 28 * MiB);
    float2* pml = (float2*)(ws + 44 * MiB);
    s8t*  Qt    = (s8t*)(ws + 76 * MiB);
    s8t*  Kt    = (s8t*)(ws + 84 * MiB);
    u16t* hh    = (u16t*)(ws + 76 * MiB);
    u16t* hl    = (u16t*)(ws + 92 * MiB);
    float2* ml  = (float2*)(ws + 108 * MiB);
    int*  rsum  = (int*)(ws + 108 * MiB + 131072);
    float2* stats = (float2*)(ws + 108 * MiB + 131072 + 8192);
    if (ws_size < 108 * MiB + 131072 + 8192 + 1024) return;

    dim3 blk(256);
    split_w<<<dim3(4096), blk, 0, stream>>>(wq, wk, wv, wp, wsp);
    gn_stats<<<dim3(128), dim3(1024), 0, stream>>>(x, stats);
    gn_apply<<<dim3(256, 4), blk, 0, stream>>>(x, gamma, beta, stats, hn_hi, hn_lo);
    dim3 gg(4, 32, 4);
    gemm512<0><<<gg, blk, 0, stream>>>(wsp + 0,       wsp + 262144,  hn_hi, hn_lo, bq, dq, zq, Qt, nullptr, nullptr);
    gemm512<0><<<gg, blk, 0, stream>>>(wsp + 524288,  wsp + 786432,  hn_hi, hn_lo, bk, dk, zk, Kt, nullptr, nullptr);
    gemm512<1><<<gg, blk, 0, stream>>>(wsp + 1048576, wsp + 1310720, hn_hi, hn_lo, bv, dv, zv, Vq, nullptr, nullptr);
    rowsum_v<<<dim3(2048), dim3(64), 0, stream>>>(Vq, rsum);
    dim3 ga(16, 32, 4);
    attn_score<0><<<ga, blk, 0, stream>>>(Qt, Kt, dq, dk, pml, nullptr, nullptr);
    reduce_ml_k<<<dim3(64), blk, 0, stream>>>(pml, ml, dw);
    attn_score<1><<<ga, blk, 0, stream>>>(Qt, Kt, dq, dk, nullptr, ml, W8);
    pv_kernel<<<gg, blk, 0, stream>>>(Vq, W8, rsum, dv, dw, hh, hl);
    gemm512<2><<<gg, blk, 0, stream>>>(wsp + 1572864, wsp + 1835008, hh, hl, bp, nullptr, nullptr, nullptr, out, x);
}

// Round 7
// 452.342 us; speedup vs baseline: 1.0844x; 1.0844x over previous
//
#include <hip/hip_runtime.h>
#include <cstdint>
#include <cstddef>

#define B_  4
#define C_  512
#define HW_ 4096

typedef unsigned short u16t;
typedef signed char s8t;
typedef __attribute__((ext_vector_type(8))) __bf16 bf16x8;
typedef __attribute__((ext_vector_type(4))) float  f32x4;
typedef __attribute__((ext_vector_type(4))) int    i32x4;

__device__ __forceinline__ u16t f2bft(float f) {            // truncate f32 -> bf16 bits
    return (u16t)(__float_as_uint(f) >> 16);
}
__device__ __forceinline__ float bf2f(u16t h) {
    return __uint_as_float(((unsigned int)h) << 16);
}
__device__ __forceinline__ f32x4 mfma16(bf16x8 a, bf16x8 b, f32x4 c) {
    return __builtin_amdgcn_mfma_f32_16x16x32_bf16(a, b, c, 0, 0, 0);
}
__device__ __forceinline__ i32x4 mfma_i8(i32x4 a, i32x4 b, i32x4 c) {
    return __builtin_amdgcn_mfma_i32_16x16x64_i8(a, b, c, 0, 0, 0);
}
// async global->LDS, 16B per lane; LDS dest = wave-uniform base + lane*16
__device__ __forceinline__ void gl16(const void* g, void* l) {
    __builtin_amdgcn_global_load_lds(
        (__attribute__((address_space(1))) unsigned int*)g,
        (__attribute__((address_space(3))) unsigned int*)l, 16, 0, 0);
}

// ---------------- K0: split 4 weight matrices into bf16 hi/lo ----------------
__global__ __launch_bounds__(256) void split_w(
    const float* __restrict__ wq_, const float* __restrict__ wk_,
    const float* __restrict__ wv_, const float* __restrict__ wp_,
    u16t* __restrict__ out)
{
    int i = blockIdx.x * 256 + threadIdx.x;     // 4*262144 total
    int mat = i >> 18, idx = i & 262143;
    const float* src = (mat == 0) ? wq_ : (mat == 1) ? wk_ : (mat == 2) ? wv_ : wp_;
    float v = src[idx];
    u16t hi = f2bft(v);
    u16t lo = f2bft(v - bf2f(hi));
    out[(size_t)mat * 524288 + idx] = hi;
    out[(size_t)mat * 524288 + 262144 + idx] = lo;
}

// ---------------- K1a: GroupNorm stats: per-(b,g) mean + rsqrt(var+eps) ------
__global__ __launch_bounds__(1024) void gn_stats(
    const float* __restrict__ x, float2* __restrict__ stats)
{
    const int tid = threadIdx.x;
    const int bg = blockIdx.x;            // b*32+g
    const int b = bg >> 5, g = bg & 31;
    const float4* x4 = (const float4*)(x + ((size_t)b * C_ + g * 16) * HW_);
    float s = 0.f, s2 = 0.f;
    for (int i = tid; i < 16384; i += 1024) {
        float4 v = x4[i];
        s  += v.x + v.y + v.z + v.w;
        s2 += v.x * v.x + v.y * v.y + v.z * v.z + v.w * v.w;
    }
    for (int off = 32; off; off >>= 1) { s += __shfl_down(s, off); s2 += __shfl_down(s2, off); }
    __shared__ float rs[16], rs2[16];
    int w = tid >> 6, lane = tid & 63;
    if (lane == 0) { rs[w] = s; rs2[w] = s2; }
    __syncthreads();
    if (tid == 0) {
        float S = 0.f, S2 = 0.f;
        #pragma unroll
        for (int i = 0; i < 16; ++i) { S += rs[i]; S2 += rs2[i]; }
        float mu = S * (1.f / 65536.f);
        float var = S2 * (1.f / 65536.f) - mu * mu;
        stats[bg] = make_float2(mu, 1.f / sqrtf(var + 1e-6f));
    }
}

// ---------------- K1b: GroupNorm apply + transpose -> hn hi/lo [b][p][c] -----
// One block: 16 p x 512 c. LDS u32 tile (hi|lo<<16), padded stride 529.
__global__ __launch_bounds__(256) void gn_apply(
    const float* __restrict__ x, const float* __restrict__ gamma,
    const float* __restrict__ beta, const float2* __restrict__ stats,
    u16t* __restrict__ hn_hi, u16t* __restrict__ hn_lo)
{
    __shared__ unsigned int tile[16 * 529];     // 33856 B
    __shared__ float sa[512], sb[512];
    const int tid = threadIdx.x;
    const int b = blockIdx.y, p0 = blockIdx.x * 16;
    for (int c = tid; c < 512; c += 256) {
        float2 st = stats[b * 32 + (c >> 4)];
        float a = st.y * gamma[c];
        sa[c] = a; sb[c] = beta[c] - st.x * a;
    }
    __syncthreads();
    const float4* x4 = (const float4*)(x + (size_t)b * C_ * HW_);
    const int f4 = tid & 3, cb = tid >> 2;      // cb 0..63
    #pragma unroll
    for (int it = 0; it < 8; ++it) {
        int c = cb + it * 64;
        float4 v = x4[(size_t)c * (HW_ / 4) + (p0 >> 2) + f4];
        float a = sa[c], bo = sb[c];
        float ys[4] = { v.x, v.y, v.z, v.w };
        #pragma unroll
        for (int j = 0; j < 4; ++j) {
            float y = ys[j] * a + bo;
            u16t hi = f2bft(y);
            u16t lo = f2bft(y - bf2f(hi));
            tile[(f4 * 4 + j) * 529 + c] = (unsigned int)hi | ((unsigned int)lo << 16);
        }
    }
    __syncthreads();
    const int p = tid & 15, seg = tid >> 4;     // seg 0..15, 32 c each
    size_t ro = ((size_t)b * HW_ + p0 + p) * C_;
    #pragma unroll
    for (int gg = 0; gg < 4; ++gg) {
        const unsigned int* src = &tile[p * 529 + seg * 32 + gg * 8];
        uint4 va = *(const uint4*)src;
        uint4 vb = *(const uint4*)(src + 4);
        uint4 hi4, lo4;
        hi4.x = (va.x & 0xFFFFu) | (va.y << 16);
        hi4.y = (va.z & 0xFFFFu) | (va.w << 16);
        hi4.z = (vb.x & 0xFFFFu) | (vb.y << 16);
        hi4.w = (vb.z & 0xFFFFu) | (vb.w << 16);
        lo4.x = (va.x >> 16) | (va.y & 0xFFFF0000u);
        lo4.y = (va.z >> 16) | (va.w & 0xFFFF0000u);
        lo4.z = (vb.x >> 16) | (vb.y & 0xFFFF0000u);
        lo4.w = (vb.z >> 16) | (vb.w & 0xFFFF0000u);
        *(uint4*)(hn_hi + ro + seg * 32 + gg * 8) = hi4;
        *(uint4*)(hn_lo + ro + seg * 32 + gg * 8) = lo4;
    }
}

// ---------------- fused QKV split-GEMM (A=[wq;wk;wv] hi/lo, B=hn hi/lo, K=512)
// mat 0 (Q), 1 (K): quant -> i8 TRANSPOSED out [p][c];  mat 2 (V): [c][p]
__global__ __launch_bounds__(256) void qkv_gemm(
    const u16t* __restrict__ wsp,
    const u16t* __restrict__ Bhi, const u16t* __restrict__ Blo,
    const float* __restrict__ bq_, const float* __restrict__ bk_,
    const float* __restrict__ bv_,
    const float* __restrict__ dq_, const float* __restrict__ zq_,
    const float* __restrict__ dk_, const float* __restrict__ zk_,
    const float* __restrict__ dv_, const float* __restrict__ zv_,
    s8t* __restrict__ Qt, s8t* __restrict__ Kt, s8t* __restrict__ Vq)
{
    __shared__ __align__(16) u16t lds[16384];
    const int tid = threadIdx.x, w = tid >> 6, lane = tid & 63;
    const int lr = lane & 15, gq = lane >> 4, wr = w >> 1, wc = w & 1;
    const int mat = blockIdx.x >> 2;
    const int m0 = (blockIdx.x & 3) * 128, n0 = blockIdx.y * 128, b = blockIdx.z;
    const size_t boff = (size_t)b * HW_ * C_;
    const u16t* Ahi = wsp + (size_t)mat * 524288;
    const u16t* Alo = Ahi + 262144;
    const u16t* gsrc = (w == 0) ? Ahi : (w == 1) ? Alo : (w == 2) ? (Bhi + boff) : (Blo + boff);
    const int rb0 = (w < 2) ? m0 : n0;
    u16t* ldst = lds + w * 4096;
    const int srow = lane >> 2, sch = lane & 3;
    const u16t* sAh = lds; const u16t* sAl = lds + 4096;
    const u16t* sBh = lds + 8192; const u16t* sBl = lds + 12288;
    f32x4 acc[4][4] = {};

    for (int kt = 0; kt < 16; ++kt) {
        const u16t* gk = gsrc + (size_t)(rb0 + srow) * C_ + kt * 32 + sch * 8;
        #pragma unroll
        for (int i = 0; i < 8; ++i) gl16(gk + i * 16 * C_, ldst + i * 512);
        __syncthreads();
        bf16x8 ah[4], al[4], bh[4], bl[4];
        #pragma unroll
        for (int m = 0; m < 4; ++m) {
            int r = wr * 64 + m * 16 + lr;
            ah[m] = *(const bf16x8*)(sAh + r * 32 + gq * 8);
            al[m] = *(const bf16x8*)(sAl + r * 32 + gq * 8);
        }
        #pragma unroll
        for (int n = 0; n < 4; ++n) {
            int r = wc * 64 + n * 16 + lr;
            bh[n] = *(const bf16x8*)(sBh + r * 32 + gq * 8);
            bl[n] = *(const bf16x8*)(sBl + r * 32 + gq * 8);
        }
        #pragma unroll
        for (int m = 0; m < 4; ++m)
            #pragma unroll
            for (int n = 0; n < 4; ++n) {
                acc[m][n] = mfma16(ah[m], bh[n], acc[m][n]);
                acc[m][n] = mfma16(ah[m], bl[n], acc[m][n]);
                acc[m][n] = mfma16(al[m], bh[n], acc[m][n]);
            }
        __syncthreads();
    }

    const float* bias = (mat == 0) ? bq_ : (mat == 1) ? bk_ : bv_;
    const float d = (mat == 0) ? *dq_ : (mat == 1) ? *dk_ : *dv_;
    const float z = (mat == 0) ? *zq_ : (mat == 1) ? *zk_ : *zv_;
    const float rd = 1.0f / d;
    s8t* outq = (mat == 0) ? Qt : (mat == 1) ? Kt : Vq;

    if (mat < 2) {
        char* T8 = (char*)lds;                   // [p 128][c 128], stride 144
        #pragma unroll
        for (int m = 0; m < 4; ++m)
            #pragma unroll
            for (int n = 0; n < 4; ++n)
                #pragma unroll
                for (int j = 0; j < 4; ++j) {
                    int row = wr * 64 + m * 16 + gq * 4 + j;     // c
                    int col = wc * 64 + n * 16 + lr;             // p
                    float val = acc[m][n][j] + bias[m0 + row];
                    float q = fminf(fmaxf(rintf(val * rd), -z), 255.f - z);
                    T8[col * 144 + row] = (char)(int)q;
                }
        __syncthreads();
        int pl = tid >> 1, hf = tid & 1;
        uint4* dst = (uint4*)(outq + ((size_t)b * HW_ + n0 + pl) * C_ + m0 + hf * 64);
        const uint4* s4 = (const uint4*)(T8 + pl * 144 + hf * 64);
        #pragma unroll
        for (int i = 0; i < 4; ++i) dst[i] = s4[i];
    } else {
        char* T8 = (char*)lds;                   // [c 128][p 128], stride 144
        #pragma unroll
        for (int m = 0; m < 4; ++m)
            #pragma unroll
            for (int n = 0; n < 4; ++n)
                #pragma unroll
                for (int j = 0; j < 4; ++j) {
                    int row = wr * 64 + m * 16 + gq * 4 + j;     // c
                    int col = wc * 64 + n * 16 + lr;             // p
                    float val = acc[m][n][j] + bias[m0 + row];
                    float q = fminf(fmaxf(rintf(val * rd), -z), 255.f - z);
                    T8[row * 144 + col] = (char)(int)q;
                }
        __syncthreads();
        int pl = tid >> 1, hf = tid & 1;
        uint4* dst = (uint4*)(outq + ((size_t)b * C_ + m0 + pl) * HW_ + n0 + hf * 64);
        const uint4* s4 = (const uint4*)(T8 + pl * 144 + hf * 64);
        #pragma unroll
        for (int i = 0; i < 4; ++i) dst[i] = s4[i];
    }
}

// ---------------- proj GEMM (A=wp hi/lo [o][c], B=h hi/lo [p][c], K=512) -----
// + bias + residual -> f32 out [c][p]
__global__ __launch_bounds__(256) void proj_gemm(
    const u16t* __restrict__ Ahi, const u16t* __restrict__ Alo,
    const u16t* __restrict__ Bhi, const u16t* __restrict__ Blo,
    const float* __restrict__ bias,
    float* __restrict__ outf, const float* __restrict__ resid)
{
    __shared__ __align__(16) u16t lds[16384];
    const int tid = threadIdx.x, w = tid >> 6, lane = tid & 63;
    const int lr = lane & 15, gq = lane >> 4, wr = w >> 1, wc = w & 1;
    const int m0 = blockIdx.x * 128, n0 = blockIdx.y * 128, b = blockIdx.z;
    const size_t boff = (size_t)b * HW_ * C_;
    const u16t* gsrc = (w == 0) ? Ahi : (w == 1) ? Alo : (w == 2) ? (Bhi + boff) : (Blo + boff);
    const int rb0 = (w < 2) ? m0 : n0;
    u16t* ldst = lds + w * 4096;
    const int srow = lane >> 2, sch = lane & 3;
    const u16t* sAh = lds; const u16t* sAl = lds + 4096;
    const u16t* sBh = lds + 8192; const u16t* sBl = lds + 12288;
    f32x4 acc[4][4] = {};

    for (int kt = 0; kt < 16; ++kt) {
        const u16t* gk = gsrc + (size_t)(rb0 + srow) * C_ + kt * 32 + sch * 8;
        #pragma unroll
        for (int i = 0; i < 8; ++i) gl16(gk + i * 16 * C_, ldst + i * 512);
        __syncthreads();
        bf16x8 ah[4], al[4], bh[4], bl[4];
        #pragma unroll
        for (int m = 0; m < 4; ++m) {
            int r = wr * 64 + m * 16 + lr;
            ah[m] = *(const bf16x8*)(sAh + r * 32 + gq * 8);
            al[m] = *(const bf16x8*)(sAl + r * 32 + gq * 8);
        }
        #pragma unroll
        for (int n = 0; n < 4; ++n) {
            int r = wc * 64 + n * 16 + lr;
            bh[n] = *(const bf16x8*)(sBh + r * 32 + gq * 8);
            bl[n] = *(const bf16x8*)(sBl + r * 32 + gq * 8);
        }
        #pragma unroll
        for (int m = 0; m < 4; ++m)
            #pragma unroll
            for (int n = 0; n < 4; ++n) {
                acc[m][n] = mfma16(ah[m], bh[n], acc[m][n]);
                acc[m][n] = mfma16(ah[m], bl[n], acc[m][n]);
                acc[m][n] = mfma16(al[m], bh[n], acc[m][n]);
            }
        __syncthreads();
    }

    #pragma unroll
    for (int m = 0; m < 4; ++m)
        #pragma unroll
        for (int n = 0; n < 4; ++n)
            #pragma unroll
            for (int j = 0; j < 4; ++j) {
                int row = wr * 64 + m * 16 + gq * 4 + j;
                int col = wc * 64 + n * 16 + lr;
                size_t o = ((size_t)b * C_ + m0 + row) * HW_ + n0 + col;
                outf[o] = acc[m][n][j] + bias[m0 + row] + resid[o];
            }
}

// ---------------- attention scores: S = Qt * Kt^T (i8, both [p][c], K=512) ---
// (proven round-5 structure)
// PASS 0: per-row partial (max, sumexp) per 128-col tile -> pml
// PASS 1: w255 = exp(s-m)*rl, round, center -128 -> W8 s8 [b][q][k]
template<int PASS>
__global__ __launch_bounds__(256) void attn_score(
    const s8t* __restrict__ Qt, const s8t* __restrict__ Kt,
    const float* __restrict__ dqp, const float* __restrict__ dkp,
    float2* __restrict__ pml, const float2* __restrict__ ml,
    s8t* __restrict__ W8)
{
    __shared__ __align__(16) char lds[18432];   // stage 16KB; epilogue P8 128*144
    __shared__ float redm[256], reds[256];
    const int tid = threadIdx.x, w = tid >> 6, lane = tid & 63;
    const int lr = lane & 15, gq = lane >> 4, wr = w >> 1, wc = w & 1;
    const int m0 = blockIdx.x * 128, n0 = blockIdx.y * 128, b = blockIdx.z;
    const size_t bo = (size_t)b * HW_ * C_;
    const s8t* gsrc = ((w < 2) ? Qt : Kt) + bo;
    const int rb0 = ((w < 2) ? m0 : n0) + (w & 1) * 64;
    char* ldst = lds + ((w < 2) ? 0 : 8192) + (w & 1) * 4096;
    const int srow = lane >> 2, sch = lane & 3;
    i32x4 acc[4][4] = {};

    for (int kt = 0; kt < 8; ++kt) {
        const s8t* gk = gsrc + (size_t)(rb0 + srow) * C_ + kt * 64 + sch * 16;
        #pragma unroll
        for (int i = 0; i < 4; ++i) gl16(gk + (size_t)i * 16 * C_, ldst + i * 1024);
        __syncthreads();
        i32x4 af[4], bf[4];
        #pragma unroll
        for (int m = 0; m < 4; ++m)
            af[m] = *(const i32x4*)(lds + (wr * 64 + m * 16 + lr) * 64 + gq * 16);
        #pragma unroll
        for (int n = 0; n < 4; ++n)
            bf[n] = *(const i32x4*)(lds + 8192 + (wc * 64 + n * 16 + lr) * 64 + gq * 16);
        #pragma unroll
        for (int m = 0; m < 4; ++m)
            #pragma unroll
            for (int n = 0; n < 4; ++n)
                acc[m][n] = mfma_i8(af[m], bf[n], acc[m][n]);
        __syncthreads();
    }

    const float sc = (*dqp) * (*dkp) * 0.044194173824159216f;  // c^-0.5, C=512
    if constexpr (PASS == 0) {
        #pragma unroll
        for (int m = 0; m < 4; ++m)
            #pragma unroll
            for (int j = 0; j < 4; ++j) {
                float v0 = (float)acc[m][0][j] * sc, v1 = (float)acc[m][1][j] * sc;
                float v2 = (float)acc[m][2][j] * sc, v3 = (float)acc[m][3][j] * sc;
                float mx = fmaxf(fmaxf(v0, v1), fmaxf(v2, v3));
                for (int off = 1; off < 16; off <<= 1) mx = fmaxf(mx, __shfl_xor(mx, off));
                float se = __expf(v0 - mx) + __expf(v1 - mx) + __expf(v2 - mx) + __expf(v3 - mx);
                for (int off = 1; off < 16; off <<= 1) se += __shfl_xor(se, off);
                if (lr == 0) {
                    int r = wr * 64 + m * 16 + gq * 4 + j;
                    redm[r * 2 + wc] = mx; reds[r * 2 + wc] = se;
                }
            }
        __syncthreads();
        if (tid < 128) {
            float ma = redm[tid * 2], mb = redm[tid * 2 + 1];
            float mm = fmaxf(ma, mb);
            float ss = reds[tid * 2] * __expf(ma - mm) + reds[tid * 2 + 1] * __expf(mb - mm);
            pml[((size_t)b * HW_ + m0 + tid) * 32 + blockIdx.y] = make_float2(mm, ss);
        }
    } else {
        char* P8 = lds;                          // [q 128][k 128], stride 144
        #pragma unroll
        for (int m = 0; m < 4; ++m)
            #pragma unroll
            for (int j = 0; j < 4; ++j) {
                int row = wr * 64 + m * 16 + gq * 4 + j;
                float2 mv = ml[(size_t)b * HW_ + m0 + row];   // (m, rl=1/(l*dw))
                #pragma unroll
                for (int n = 0; n < 4; ++n) {
                    int col = wc * 64 + n * 16 + lr;
                    float sv = __builtin_fmaf((float)acc[m][n][j], sc, -mv.x);
                    float r = rintf(__expf(sv) * mv.y);
                    r = fminf(fmaxf(r, 0.f), 255.f);
                    P8[row * 144 + col] = (char)((int)r - 128);
                }
            }
        __syncthreads();
        int pl = tid >> 1, hf = tid & 1;
        uint4* dst = (uint4*)(W8 + ((size_t)b * HW_ + m0 + pl) * HW_ + n0 + hf * 64);
        const uint4* s4 = (const uint4*)(P8 + pl * 144 + hf * 64);
        #pragma unroll
        for (int i = 0; i < 4; ++i) dst[i] = s4[i];
    }
}

// ---------------- merge per-tile (m,l) partials -> (m, 1/(l*dw)) -------------
__global__ __launch_bounds__(256) void reduce_ml_k(
    const float2* __restrict__ pml, float2* __restrict__ ml,
    const float* __restrict__ dwp)
{
    int idx = blockIdx.x * 256 + threadIdx.x;   // < B_*HW_
    const float2* p = pml + (size_t)idx * 32;
    float2 vv[32];
    float mm = -3.402823466e38f;
    #pragma unroll
    for (int i = 0; i < 32; ++i) { vv[i] = p[i]; mm = fmaxf(mm, vv[i].x); }
    float l = 0.f;
    #pragma unroll
    for (int i = 0; i < 32; ++i) l += vv[i].y * __expf(vv[i].x - mm);
    ml[idx] = make_float2(mm, 1.0f / (l * (*dwp)));
}

// ---------------- per-(b,c) row sums of centered V ---------------------------
__global__ __launch_bounds__(64) void rowsum_v(
    const s8t* __restrict__ V, int* __restrict__ rsum)
{
    const int row = blockIdx.x, lane = threadIdx.x;   // 2048 rows
    const int4* src = (const int4*)(V + (size_t)row * HW_);
    int s = 0;
    #pragma unroll
    for (int it = 0; it < 4; ++it) {
        int4 v = src[it * 64 + lane];
        int ww[4] = { v.x, v.y, v.z, v.w };
        #pragma unroll
        for (int d = 0; d < 4; ++d) {
            int xv = ww[d];
            s += (int)(s8t)(xv) + (int)(s8t)(xv >> 8)
               + (int)(s8t)(xv >> 16) + (int)(s8t)(xv >> 24);
        }
    }
    #pragma unroll
    for (int off = 32; off; off >>= 1) s += __shfl_down(s, off);
    if (lane == 0) rsum[row] = s;
}

// ---------------- PV: h[c][q] = (VW' + 128*rowsumV) * dv*dw  (i8 MFMA) -------
// double-buffered prefetch, 128x128 tile. (round-6 version, kept)
__global__ __launch_bounds__(256) void pv_kernel(
    const s8t* __restrict__ V, const s8t* __restrict__ W8,
    const int* __restrict__ rsum,
    const float* __restrict__ dvp, const float* __restrict__ dwp,
    u16t* __restrict__ h_hi, u16t* __restrict__ h_lo)
{
    __shared__ __align__(16) char lds[34816];   // 2 x 16K stage; epilogue T u16 128*136
    const int tid = threadIdx.x, w = tid >> 6, lane = tid & 63;
    const int lr = lane & 15, gq = lane >> 4, wr = w >> 1, wc = w & 1;
    const int m0 = blockIdx.x * 128, n0 = blockIdx.y * 128, b = blockIdx.z;
    const int srow = lane >> 2, sch = lane & 3;
    const s8t* gbase = (w < 2)
        ? (V  + ((size_t)(b * C_  + m0 + (w & 1) * 64 + srow)) * HW_)
        : (W8 + ((size_t)b * HW_ + n0 + (w & 1) * 64 + srow) * HW_);
    char* ldst = lds + ((w < 2) ? 0 : 8192) + (w & 1) * 4096;
    i32x4 acc[4][4] = {};

    // prologue: stage kt=0 into buffer 0
    {
        const s8t* gk = gbase + sch * 16;
        #pragma unroll
        for (int i = 0; i < 4; ++i) gl16(gk + (size_t)i * 16 * HW_, ldst + i * 1024);
    }
    __syncthreads();
    int cur = 0;
    for (int kt = 0; kt < 64; ++kt) {
        if (kt < 63) {
            const s8t* gk = gbase + (kt + 1) * 64 + sch * 16;
            char* nd = ldst + (cur ^ 1) * 16384;
            #pragma unroll
            for (int i = 0; i < 4; ++i) gl16(gk + (size_t)i * 16 * HW_, nd + i * 1024);
        }
        const char* rb = lds + cur * 16384;
        i32x4 af[4], bf[4];
        #pragma unroll
        for (int m = 0; m < 4; ++m)
            af[m] = *(const i32x4*)(rb + (wr * 64 + m * 16 + lr) * 64 + gq * 16);
        #pragma unroll
        for (int n = 0; n < 4; ++n)
            bf[n] = *(const i32x4*)(rb + 8192 + (wc * 64 + n * 16 + lr) * 64 + gq * 16);
        #pragma unroll
        for (int m = 0; m < 4; ++m)
            #pragma unroll
            for (int n = 0; n < 4; ++n)
                acc[m][n] = mfma_i8(af[m], bf[n], acc[m][n]);
        __syncthreads();
        cur ^= 1;
    }

    const float scl = (*dvp) * (*dwp);
    int rsv[4][4];
    #pragma unroll
    for (int m = 0; m < 4; ++m)
        #pragma unroll
        for (int j = 0; j < 4; ++j)
            rsv[m][j] = rsum[(size_t)b * C_ + m0 + wr * 64 + m * 16 + gq * 4 + j];

    u16t* T = (u16t*)lds;                        // [p 128][c 128], stride 136
    // hi pass
    #pragma unroll
    for (int m = 0; m < 4; ++m)
        #pragma unroll
        for (int n = 0; n < 4; ++n)
            #pragma unroll
            for (int j = 0; j < 4; ++j) {
                int row = wr * 64 + m * 16 + gq * 4 + j;
                int col = wc * 64 + n * 16 + lr;
                float h = (float)(acc[m][n][j] + 128 * rsv[m][j]) * scl;
                T[col * 136 + row] = f2bft(h);
            }
    __syncthreads();
    {
        int pl = tid >> 1, hf = tid & 1;
        uint4* dst = (uint4*)(h_hi + ((size_t)b * HW_ + n0 + pl) * C_ + m0 + hf * 64);
        const uint4* s4 = (const uint4*)(T + pl * 136 + hf * 64);
        #pragma unroll
        for (int i = 0; i < 8; ++i) dst[i] = s4[i];
    }
    __syncthreads();
    // lo pass
    #pragma unroll
    for (int m = 0; m < 4; ++m)
        #pragma unroll
        for (int n = 0; n < 4; ++n)
            #pragma unroll
            for (int j = 0; j < 4; ++j) {
                int row = wr * 64 + m * 16 + gq * 4 + j;
                int col = wc * 64 + n * 16 + lr;
                float h = (float)(acc[m][n][j] + 128 * rsv[m][j]) * scl;
                u16t hi = f2bft(h);
                T[col * 136 + row] = f2bft(h - bf2f(hi));
            }
    __syncthreads();
    {
        int pl = tid >> 1, hf = tid & 1;
        uint4* dst = (uint4*)(h_lo + ((size_t)b * HW_ + n0 + pl) * C_ + m0 + hf * 64);
        const uint4* s4 = (const uint4*)(T + pl * 136 + hf * 64);
        #pragma unroll
        for (int i = 0; i < 8; ++i) dst[i] = s4[i];
    }
}

// ---------------- launcher ---------------------------------------------------
extern "C" void kernel_launch(void* const* d_in, const int* in_sizes, int n_in,
                              void* d_out, int out_size, void* d_ws, size_t ws_size,
                              hipStream_t stream)
{
    const float* x     = (const float*)d_in[0];
    const float* gamma = (const float*)d_in[1];
    const float* beta  = (const float*)d_in[2];
    const float* wq = (const float*)d_in[3];
    const float* bq = (const float*)d_in[4];
    const float* wk = (const float*)d_in[5];
    const float* bk = (const float*)d_in[6];
    const float* wv = (const float*)d_in[7];
    const float* bv = (const float*)d_in[8];
    const float* wp = (const float*)d_in[9];
    const float* bp = (const float*)d_in[10];
    const float* dq = (const float*)d_in[11];
    const float* zq = (const float*)d_in[12];
    const float* dk = (const float*)d_in[13];
    const float* zk = (const float*)d_in[14];
    const float* dv = (const float*)d_in[15];
    const float* zv = (const float*)d_in[16];
    const float* dw = (const float*)d_in[17];
    float* out = (float*)d_out;
    char* ws = (char*)d_ws;
    const size_t MiB = 1048576;

    // Overlay plan (peak 108 MiB + ~141 KB):
    //  [0,4)     wsp (bf16 hi/lo weights)                split_w -> proj
    //  [4,12)    Vq (i8 [c][p])                          qkv -> pv
    //  [12,76)   W8 (s8 [q][k])                          attn1 -> pv
    //    [12,28) hn_hi, [28,44) hn_lo (dead before attn1)
    //    [44,48) pml (dead before attn1)
    //  [76,108)  hh [76,92), hl [92,108)                 pv -> proj
    //    [76,84) Qt, [84,92) Kt (dead before pv writes hh)
    //  [108,..)  ml 128KB, rsum 8KB, stats 1KB
    u16t* wsp   = (u16t*)ws;
    s8t*  Vq    = (s8t*)(ws + 4 * MiB);
    s8t*  W8    = (s8t*)(ws + 12 * MiB);
    u16t* hn_hi = (u16t*)(ws + 12 * MiB);
    u16t* hn_lo = (u16t*)(ws + 28 * MiB);
    float2* pml = (float2*)(ws + 44 * MiB);
    s8t*  Qt    = (s8t*)(ws + 76 * MiB);
    s8t*  Kt    = (s8t*)(ws + 84 * MiB);
    u16t* hh    = (u16t*)(ws + 76 * MiB);
    u16t* hl    = (u16t*)(ws + 92 * MiB);
    float2* ml  = (float2*)(ws + 108 * MiB);
    int*  rsum  = (int*)(ws + 108 * MiB + 131072);
    float2* stats = (float2*)(ws + 108 * MiB + 131072 + 8192);
    if (ws_size < 108 * MiB + 131072 + 8192 + 1024) return;

    dim3 blk(256);
    split_w<<<dim3(4096), blk, 0, stream>>>(wq, wk, wv, wp, wsp);
    gn_stats<<<dim3(128), dim3(1024), 0, stream>>>(x, stats);
    gn_apply<<<dim3(256, 4), blk, 0, stream>>>(x, gamma, beta, stats, hn_hi, hn_lo);
    qkv_gemm<<<dim3(12, 32, 4), blk, 0, stream>>>(
        wsp, hn_hi, hn_lo, bq, bk, bv, dq, zq, dk, zk, dv, zv, Qt, Kt, Vq);
    rowsum_v<<<dim3(2048), dim3(64), 0, stream>>>(Vq, rsum);
    dim3 ga(32, 32, 4);
    attn_score<0><<<ga, blk, 0, stream>>>(Qt, Kt, dq, dk, pml, nullptr, nullptr);
    reduce_ml_k<<<dim3(64), blk, 0, stream>>>(pml, ml, dw);
    attn_score<1><<<ga, blk, 0, stream>>>(Qt, Kt, dq, dk, nullptr, ml, W8);
    dim3 gg(4, 32, 4);
    pv_kernel<<<gg, blk, 0, stream>>>(Vq, W8, rsum, dv, dw, hh, hl);
    proj_gemm<<<gg, blk, 0, stream>>>(wsp + 1572864, wsp + 1835008, hh, hl, bp, out, x);
}